// Round 5
// baseline (149.697 us; speedup 1.0000x reference)
//
#include <hip/hip_runtime.h>
#include <hip/hip_bf16.h>

#define LRALPHA 0.2f
#define L2E 1.4426950408889634f
#define NN 8192
#define FIN 128
#define FOUT 64
#define TI 16
#define TJ 256
#define NTL (NN / TJ)       // 32 tiles of 256 cols
#define TPB 16              // tiles per block (j-range split in half)

typedef __attribute__((ext_vector_type(4))) float f32x4;
typedef __attribute__((ext_vector_type(8))) short bf16x8;
typedef __attribute__((ext_vector_type(4))) int int4v;

__device__ __forceinline__ void barrier_lgkm() {
  asm volatile("s_waitcnt lgkmcnt(0)\n\ts_barrier" ::: "memory");
}

// ---------------------------------------------------------------------------
// kernel 0: adj (268 MB int32) -> 1-bit mask (8 MB). Perfectly linear read,
// 2 chunks (2 KB) per iteration for MLP. mask[c*4+g] bit b = adj col c*256+g*64+b.
// ---------------------------------------------------------------------------
__global__ __launch_bounds__(256) void compress_kernel(
    const int* __restrict__ adj, unsigned long long* __restrict__ mask)
{
  const int l = threadIdx.x & 63;
  const int wid = (blockIdx.x * 256 + threadIdx.x) >> 6;
  const int nw = (gridDim.x * 256) >> 6;        // 8192 waves
  const int npairs = NN * (NN / 512);           // 131072 chunk-pairs
  for (int pc = wid; pc < npairs; pc += nw) {
    const int* base = adj + (size_t)pc * 512 + l;
    int a0 = __builtin_nontemporal_load(base);
    int a1 = __builtin_nontemporal_load(base + 64);
    int a2 = __builtin_nontemporal_load(base + 128);
    int a3 = __builtin_nontemporal_load(base + 192);
    int a4 = __builtin_nontemporal_load(base + 256);
    int a5 = __builtin_nontemporal_load(base + 320);
    int a6 = __builtin_nontemporal_load(base + 384);
    int a7 = __builtin_nontemporal_load(base + 448);
    unsigned long long b0 = __ballot(a0 > 0);
    unsigned long long b1 = __ballot(a1 > 0);
    unsigned long long b2 = __ballot(a2 > 0);
    unsigned long long b3 = __ballot(a3 > 0);
    unsigned long long b4 = __ballot(a4 > 0);
    unsigned long long b5 = __ballot(a5 > 0);
    unsigned long long b6 = __ballot(a6 > 0);
    unsigned long long b7 = __ballot(a7 > 0);
    if (l < 8) {
      unsigned long long v = b0;
      v = l == 1 ? b1 : v;
      v = l == 2 ? b2 : v;
      v = l == 3 ? b3 : v;
      v = l == 4 ? b4 : v;
      v = l == 5 ? b5 : v;
      v = l == 6 ? b6 : v;
      v = l == 7 ? b7 : v;
      mask[(size_t)pc * 8 + l] = v;
    }
  }
}

// ---------------------------------------------------------------------------
// kernel 1: h = inp @ W (fp32), f1/f2 (prescaled by log2(e)), hT bf16
// ---------------------------------------------------------------------------
__global__ __launch_bounds__(256) void prep_kernel(
    const float* __restrict__ inp, const float* __restrict__ Wg,
    const float* __restrict__ ag, float* __restrict__ f1,
    float* __restrict__ f2, unsigned short* __restrict__ hT)
{
  __shared__ alignas(16) float WlT[FOUT][FIN + 4];
  const int t = threadIdx.x;
  for (int i = t; i < FIN * FOUT; i += 256)
    WlT[i & 63][i >> 6] = Wg[i];
  __syncthreads();

  const int lane = t & 63;
  const int row0 = blockIdx.x * 16 + (t >> 6) * 4;

  float h0 = 0.f, h1 = 0.f, h2 = 0.f, h3 = 0.f;
  for (int kk = 0; kk < FIN; kk += 4) {
    f32x4 wv = *(const f32x4*)&WlT[lane][kk];
    f32x4 r0 = *(const f32x4*)&inp[(row0 + 0) * FIN + kk];
    f32x4 r1 = *(const f32x4*)&inp[(row0 + 1) * FIN + kk];
    f32x4 r2 = *(const f32x4*)&inp[(row0 + 2) * FIN + kk];
    f32x4 r3 = *(const f32x4*)&inp[(row0 + 3) * FIN + kk];
    h0 += r0[0]*wv[0] + r0[1]*wv[1] + r0[2]*wv[2] + r0[3]*wv[3];
    h1 += r1[0]*wv[0] + r1[1]*wv[1] + r1[2]*wv[2] + r1[3]*wv[3];
    h2 += r2[0]*wv[0] + r2[1]*wv[1] + r2[2]*wv[2] + r2[3]*wv[3];
    h3 += r3[0]*wv[0] + r3[1]*wv[1] + r3[2]*wv[2] + r3[3]*wv[3];
  }

  const float a1v = ag[lane], a2v = ag[64 + lane];
  float hv[4] = {h0, h1, h2, h3};
#pragma unroll
  for (int rr = 0; rr < 4; ++rr) {
    float c1 = hv[rr] * a1v;
    float c2 = hv[rr] * a2v;
#pragma unroll
    for (int off = 32; off > 0; off >>= 1) {
      c1 += __shfl_xor(c1, off);
      c2 += __shfl_xor(c2, off);
    }
    if (lane == 0) { f1[row0 + rr] = c1 * L2E; f2[row0 + rr] = c2 * L2E; }
    __hip_bfloat16 hb = __float2bfloat16(hv[rr]);
    hT[lane * NN + row0 + rr] = __builtin_bit_cast(unsigned short, hb);
  }
}

// ---------------------------------------------------------------------------
// kernel 2: global max of (scaled) f2
// ---------------------------------------------------------------------------
__global__ __launch_bounds__(256) void f2max_kernel(
    const float* __restrict__ f2, float* __restrict__ f2m)
{
  const int t = threadIdx.x;
  float m = -1e30f;
  for (int i = t; i < NN / 4; i += 256) {
    f32x4 v = ((const f32x4*)f2)[i];
    m = fmaxf(fmaxf(m, fmaxf(v[0], v[1])), fmaxf(v[2], v[3]));
  }
#pragma unroll
  for (int off = 32; off > 0; off >>= 1)
    m = fmaxf(m, __shfl_xor(m, off));
  __shared__ float ms[4];
  if ((t & 63) == 0) ms[t >> 6] = m;
  __syncthreads();
  if (t == 0)
    f2m[0] = fmaxf(fmaxf(ms[0], ms[1]), fmaxf(ms[2], ms[3]));
}

// ---------------------------------------------------------------------------
// kernel 3: masked-softmax attention PV, mask-fed, exp2-domain P-gen,
// v_perm bf16 packing. grid = 1024 (row-block x j-half), 4 blocks/CU.
// Partial acc/rowsum -> ws; epilogue combines.
// ---------------------------------------------------------------------------
__global__ __launch_bounds__(256, 4) void gat_main(
    const unsigned long long* __restrict__ mask,
    const float* __restrict__ f1g, const float* __restrict__ f2g,
    const float* __restrict__ f2m, const unsigned short* __restrict__ hTg,
    float* __restrict__ pacc, float* __restrict__ prs)
{
  __shared__ alignas(16) unsigned short Pl[4][TI][TJ + 8];

  const int t = threadIdx.x;
  const int l = t & 63;
  const int w = t >> 6;
  const int rb = blockIdx.x >> 1;
  const int h  = blockIdx.x & 1;
  const int i0 = rb * TI;
  const int g  = l >> 4;
  const int p0t = h * TPB;

  const float fmv = f2m[0];
  float c1q[4], c2q[4];
#pragma unroll
  for (int q = 0; q < 4; ++q) {
    float f1s = f1g[i0 + 4 * w + q];
    float M = f1s + fmv;
    float mr = fmaxf(M, LRALPHA * M);
    c1q[q] = f1s - mr;
    c2q[q] = LRALPHA * f1s - mr;
  }

  const unsigned long long* mr0 = mask + ((size_t)(i0 + 4*w + 0) * NTL) * 4 + g;
  const unsigned long long* mr1 = mask + ((size_t)(i0 + 4*w + 1) * NTL) * 4 + g;
  const unsigned long long* mr2 = mask + ((size_t)(i0 + 4*w + 2) * NTL) * 4 + g;
  const unsigned long long* mr3 = mask + ((size_t)(i0 + 4*w + 3) * NTL) * 4 + g;
  const int mshift = (l & 15) * 4;

  const float* f2p = f2g + 4 * l;
  const unsigned short* hp = hTg + (size_t)(w * 16 + (l & 15)) * NN + g * 8;

  f32x4 acc = {0.f, 0.f, 0.f, 0.f};
  float rs0 = 0.f, rs1 = 0.f, rs2 = 0.f, rs3 = 0.f;

#define PRODUCE(K, MM0, MM1, MM2, MM3, FF)                                     \
  {                                                                            \
    float F5x = LRALPHA * FF[0], F5y = LRALPHA * FF[1],                        \
          F5z = LRALPHA * FF[2], F5w = LRALPHA * FF[3];                        \
    _Pragma("unroll")                                                          \
    for (int q = 0; q < 4; ++q) {                                              \
      unsigned long long mm = q == 0 ? MM0 : q == 1 ? MM1 : q == 2 ? MM2 : MM3;\
      unsigned nib = (unsigned)(mm >> mshift) & 0xFu;                          \
      float z0 = fmaxf(c1q[q] + FF[0], c2q[q] + F5x);                          \
      float z1 = fmaxf(c1q[q] + FF[1], c2q[q] + F5y);                          \
      float z2 = fmaxf(c1q[q] + FF[2], c2q[q] + F5z);                          \
      float z3 = fmaxf(c1q[q] + FF[3], c2q[q] + F5w);                          \
      z0 = (nib & 1u) ? z0 : -1000.f;                                          \
      z1 = (nib & 2u) ? z1 : -1000.f;                                          \
      z2 = (nib & 4u) ? z2 : -1000.f;                                          \
      z3 = (nib & 8u) ? z3 : -1000.f;                                          \
      float p0 = __builtin_amdgcn_exp2f(z0);                                   \
      float p1 = __builtin_amdgcn_exp2f(z1);                                   \
      float p2 = __builtin_amdgcn_exp2f(z2);                                   \
      float p3 = __builtin_amdgcn_exp2f(z3);                                   \
      float pS = (p0 + p1) + (p2 + p3);                                        \
      if (q == 0) rs0 += pS;                                                   \
      else if (q == 1) rs1 += pS;                                              \
      else if (q == 2) rs2 += pS;                                              \
      else rs3 += pS;                                                          \
      unsigned r0 = __builtin_bit_cast(unsigned, p0) + 0x8000u;                \
      unsigned r1 = __builtin_bit_cast(unsigned, p1) + 0x8000u;                \
      unsigned r2 = __builtin_bit_cast(unsigned, p2) + 0x8000u;                \
      unsigned r3 = __builtin_bit_cast(unsigned, p3) + 0x8000u;                \
      unsigned pk01 = __builtin_amdgcn_perm(r1, r0, 0x07060302u);              \
      unsigned pk23 = __builtin_amdgcn_perm(r3, r2, 0x07060302u);              \
      unsigned long long pk = (unsigned long long)pk01 |                       \
                              ((unsigned long long)pk23 << 32);                \
      *(unsigned long long*)&Pl[(K) & 3][4 * w + q][4 * l] = pk;               \
    }                                                                          \
  }

#define LOADR(MM0, MM1, MM2, MM3, FF, K)                                       \
  { int _k = (K) < TPB ? (K) : (TPB - 1);                                      \
    int _p = p0t + _k;                                                         \
    MM0 = mr0[_p * 4]; MM1 = mr1[_p * 4];                                      \
    MM2 = mr2[_p * 4]; MM3 = mr3[_p * 4];                                      \
    FF = *(const f32x4*)(f2p + _p * TJ); }

  unsigned long long m0, m1, m2, m3;
  f32x4 ff;

  LOADR(m0, m1, m2, m3, ff, 0);
  PRODUCE(0, m0, m1, m2, m3, ff);
  LOADR(m0, m1, m2, m3, ff, 1);
  PRODUCE(1, m0, m1, m2, m3, ff);
  LOADR(m0, m1, m2, m3, ff, 2);

  for (int k = 0; k < TPB; ++k) {
    if (k < TPB - 2) {
      PRODUCE(k + 2, m0, m1, m2, m3, ff);
      LOADR(m0, m1, m2, m3, ff, k + 3);
    }
    barrier_lgkm();
    const unsigned short* pa = &Pl[k & 3][0][0] + (l & 15) * (TJ + 8) + g * 8;
    const unsigned short* pb = hp + (size_t)(p0t + k) * TJ;
#pragma unroll
    for (int kw = 0; kw < 8; ++kw) {
      bf16x8 av = *(const bf16x8*)(pa + kw * 32);
      bf16x8 bv = *(const bf16x8*)(pb + kw * 32);
      acc = __builtin_amdgcn_mfma_f32_16x16x32_bf16(av, bv, acc, 0, 0, 0);
    }
  }
#undef PRODUCE
#undef LOADR

  // wave-level row sums -> partial rs
  float rsq[4] = {rs0, rs1, rs2, rs3};
#pragma unroll
  for (int q = 0; q < 4; ++q) {
    float r = rsq[q];
#pragma unroll
    for (int off = 32; off > 0; off >>= 1)
      r += __shfl_xor(r, off);
    if (l == 0) prs[(size_t)h * NN + i0 + 4 * w + q] = r;
  }

  // partial acc: row = g*4 + q, col = w*16 + (l&15)
  float* po = pacc + (size_t)h * NN * FOUT
            + (size_t)(i0 + g * 4) * FOUT + (w * 16 + (l & 15));
#pragma unroll
  for (int q = 0; q < 4; ++q)
    po[(size_t)q * FOUT] = acc[q];
}

// ---------------------------------------------------------------------------
// kernel 4: combine halves, BN, ELU
// ---------------------------------------------------------------------------
__global__ __launch_bounds__(256) void epilogue_kernel(
    const float* __restrict__ pacc, const float* __restrict__ prs,
    const float* __restrict__ bng, const float* __restrict__ bnb,
    const float* __restrict__ bnm, const float* __restrict__ bnv,
    float* __restrict__ out)
{
  const int idx = blockIdx.x * 256 + threadIdx.x;
  const int i = idx >> 6;
  const int c = idx & 63;
  float s = pacc[idx] + pacc[(size_t)NN * FOUT + idx];
  float r = prs[i] + prs[NN + i];
  float v = s / r;
  v = (v - bnm[c]) * rsqrtf(bnv[c] + 1e-5f) * bng[c] + bnb[c];
  out[idx] = v > 0.f ? v : expm1f(v);
}

// ---------------------------------------------------------------------------
extern "C" void kernel_launch(void* const* d_in, const int* in_sizes, int n_in,
                              void* d_out, int out_size, void* d_ws, size_t ws_size,
                              hipStream_t stream)
{
  (void)in_sizes; (void)n_in; (void)out_size; (void)ws_size;
  const float* inp = (const float*)d_in[0];
  const int*   adj = (const int*)d_in[1];
  const float* Wg  = (const float*)d_in[2];
  const float* ag  = (const float*)d_in[3];
  const float* bng = (const float*)d_in[4];
  const float* bnb = (const float*)d_in[5];
  const float* bnm = (const float*)d_in[6];
  const float* bnv = (const float*)d_in[7];
  float* out = (float*)d_out;

  char* ws = (char*)d_ws;
  unsigned short* hT = (unsigned short*)ws;                      // 1 MiB
  float* f1  = (float*)(ws + (size_t)NN * FOUT * 2);             // 32 KiB
  float* f2  = f1 + NN;                                          // 32 KiB
  float* f2m = f2 + NN;                                          // 4 B
  unsigned long long* mask =
      (unsigned long long*)(ws + (size_t)2 * 1024 * 1024);       // 8 MiB
  float* pacc = (float*)(ws + (size_t)10 * 1024 * 1024);         // 4 MiB
  float* prs  = (float*)(ws + (size_t)14 * 1024 * 1024);         // 64 KiB

  compress_kernel<<<2048, 256, 0, stream>>>(adj, mask);
  prep_kernel<<<NN / 16, 256, 0, stream>>>(inp, Wg, ag, f1, f2, hT);
  f2max_kernel<<<1, 256, 0, stream>>>(f2, f2m);
  gat_main<<<(NN / TI) * 2, 256, 0, stream>>>(mask, f1, f2, f2m, hT, pacc, prs);
  epilogue_kernel<<<NN * FOUT / 256, 256, 0, stream>>>(pacc, prs, bng, bnb,
                                                       bnm, bnv, out);
}

// Round 6
// 145.797 us; speedup vs baseline: 1.0267x; 1.0267x over previous
//
#include <hip/hip_runtime.h>
#include <hip/hip_bf16.h>

#define LRALPHA 0.2f
#define L2E 1.4426950408889634f
#define NN 8192
#define FIN 128
#define FOUT 64
#define TI 16
#define TJ 256
#define NTL (NN / TJ)       // 32 tiles of 256 cols
#define TPB 16              // tiles per block (j-range split in half)

typedef __attribute__((ext_vector_type(4))) float f32x4;
typedef __attribute__((ext_vector_type(8))) short bf16x8;
typedef __attribute__((ext_vector_type(4))) int int4v;

__device__ __forceinline__ void barrier_lgkm() {
  asm volatile("s_waitcnt lgkmcnt(0)\n\ts_barrier" ::: "memory");
}

// ---------------------------------------------------------------------------
// kernel 0: adj (268 MB int32) -> 1-bit mask (8 MB). Perfectly linear read,
// 2 KB per wave-iteration. PLAIN loads (nontemporal removed: NT was capping
// read BW at ~2.4 TB/s in rounds 1-5).
// mask[c*4+g] bit b = adj col c*256 + g*64 + b.
// ---------------------------------------------------------------------------
__global__ __launch_bounds__(256) void compress_kernel(
    const int* __restrict__ adj, unsigned long long* __restrict__ mask)
{
  const int l = threadIdx.x & 63;
  const int wid = (blockIdx.x * 256 + threadIdx.x) >> 6;
  const int nw = (gridDim.x * 256) >> 6;        // 8192 waves
  const int npairs = NN * (NN / 512);           // 131072 chunk-pairs
  for (int pc = wid; pc < npairs; pc += nw) {
    const int* base = adj + (size_t)pc * 512 + l;
    int a0 = base[0];
    int a1 = base[64];
    int a2 = base[128];
    int a3 = base[192];
    int a4 = base[256];
    int a5 = base[320];
    int a6 = base[384];
    int a7 = base[448];
    unsigned long long b0 = __ballot(a0 > 0);
    unsigned long long b1 = __ballot(a1 > 0);
    unsigned long long b2 = __ballot(a2 > 0);
    unsigned long long b3 = __ballot(a3 > 0);
    unsigned long long b4 = __ballot(a4 > 0);
    unsigned long long b5 = __ballot(a5 > 0);
    unsigned long long b6 = __ballot(a6 > 0);
    unsigned long long b7 = __ballot(a7 > 0);
    if (l < 8) {
      unsigned long long v = b0;
      v = l == 1 ? b1 : v;
      v = l == 2 ? b2 : v;
      v = l == 3 ? b3 : v;
      v = l == 4 ? b4 : v;
      v = l == 5 ? b5 : v;
      v = l == 6 ? b6 : v;
      v = l == 7 ? b7 : v;
      mask[(size_t)pc * 8 + l] = v;
    }
  }
}

// ---------------------------------------------------------------------------
// kernel 1: h = inp @ W (fp32), f1/f2 (prescaled by log2(e)), hT bf16
// ---------------------------------------------------------------------------
__global__ __launch_bounds__(256) void prep_kernel(
    const float* __restrict__ inp, const float* __restrict__ Wg,
    const float* __restrict__ ag, float* __restrict__ f1,
    float* __restrict__ f2, unsigned short* __restrict__ hT)
{
  __shared__ alignas(16) float WlT[FOUT][FIN + 4];
  const int t = threadIdx.x;
  for (int i = t; i < FIN * FOUT; i += 256)
    WlT[i & 63][i >> 6] = Wg[i];
  __syncthreads();

  const int lane = t & 63;
  const int row0 = blockIdx.x * 16 + (t >> 6) * 4;

  float h0 = 0.f, h1 = 0.f, h2 = 0.f, h3 = 0.f;
  for (int kk = 0; kk < FIN; kk += 4) {
    f32x4 wv = *(const f32x4*)&WlT[lane][kk];
    f32x4 r0 = *(const f32x4*)&inp[(row0 + 0) * FIN + kk];
    f32x4 r1 = *(const f32x4*)&inp[(row0 + 1) * FIN + kk];
    f32x4 r2 = *(const f32x4*)&inp[(row0 + 2) * FIN + kk];
    f32x4 r3 = *(const f32x4*)&inp[(row0 + 3) * FIN + kk];
    h0 += r0[0]*wv[0] + r0[1]*wv[1] + r0[2]*wv[2] + r0[3]*wv[3];
    h1 += r1[0]*wv[0] + r1[1]*wv[1] + r1[2]*wv[2] + r1[3]*wv[3];
    h2 += r2[0]*wv[0] + r2[1]*wv[1] + r2[2]*wv[2] + r2[3]*wv[3];
    h3 += r3[0]*wv[0] + r3[1]*wv[1] + r3[2]*wv[2] + r3[3]*wv[3];
  }

  const float a1v = ag[lane], a2v = ag[64 + lane];
  float hv[4] = {h0, h1, h2, h3};
#pragma unroll
  for (int rr = 0; rr < 4; ++rr) {
    float c1 = hv[rr] * a1v;
    float c2 = hv[rr] * a2v;
#pragma unroll
    for (int off = 32; off > 0; off >>= 1) {
      c1 += __shfl_xor(c1, off);
      c2 += __shfl_xor(c2, off);
    }
    if (lane == 0) { f1[row0 + rr] = c1 * L2E; f2[row0 + rr] = c2 * L2E; }
    __hip_bfloat16 hb = __float2bfloat16(hv[rr]);
    hT[lane * NN + row0 + rr] = __builtin_bit_cast(unsigned short, hb);
  }
}

// ---------------------------------------------------------------------------
// kernel 2: global max of (scaled) f2
// ---------------------------------------------------------------------------
__global__ __launch_bounds__(256) void f2max_kernel(
    const float* __restrict__ f2, float* __restrict__ f2m)
{
  const int t = threadIdx.x;
  float m = -1e30f;
  for (int i = t; i < NN / 4; i += 256) {
    f32x4 v = ((const f32x4*)f2)[i];
    m = fmaxf(fmaxf(m, fmaxf(v[0], v[1])), fmaxf(v[2], v[3]));
  }
#pragma unroll
  for (int off = 32; off > 0; off >>= 1)
    m = fmaxf(m, __shfl_xor(m, off));
  __shared__ float ms[4];
  if ((t & 63) == 0) ms[t >> 6] = m;
  __syncthreads();
  if (t == 0)
    f2m[0] = fmaxf(fmaxf(ms[0], ms[1]), fmaxf(ms[2], ms[3]));
}

// ---------------------------------------------------------------------------
// kernel 3: masked-softmax attention PV, mask-fed, exp2-domain P-gen,
// v_perm bf16 packing. grid = 1024 (row-block x j-half), 4 blocks/CU.
// Partial acc/rowsum -> ws; epilogue combines.
// ---------------------------------------------------------------------------
__global__ __launch_bounds__(256, 4) void gat_main(
    const unsigned long long* __restrict__ mask,
    const float* __restrict__ f1g, const float* __restrict__ f2g,
    const float* __restrict__ f2m, const unsigned short* __restrict__ hTg,
    float* __restrict__ pacc, float* __restrict__ prs)
{
  __shared__ alignas(16) unsigned short Pl[4][TI][TJ + 8];

  const int t = threadIdx.x;
  const int l = t & 63;
  const int w = t >> 6;
  const int rb = blockIdx.x >> 1;
  const int h  = blockIdx.x & 1;
  const int i0 = rb * TI;
  const int g  = l >> 4;
  const int p0t = h * TPB;

  const float fmv = f2m[0];
  float c1q[4], c2q[4];
#pragma unroll
  for (int q = 0; q < 4; ++q) {
    float f1s = f1g[i0 + 4 * w + q];
    float M = f1s + fmv;
    float mr = fmaxf(M, LRALPHA * M);
    c1q[q] = f1s - mr;
    c2q[q] = LRALPHA * f1s - mr;
  }

  const unsigned long long* mr0 = mask + ((size_t)(i0 + 4*w + 0) * NTL) * 4 + g;
  const unsigned long long* mr1 = mask + ((size_t)(i0 + 4*w + 1) * NTL) * 4 + g;
  const unsigned long long* mr2 = mask + ((size_t)(i0 + 4*w + 2) * NTL) * 4 + g;
  const unsigned long long* mr3 = mask + ((size_t)(i0 + 4*w + 3) * NTL) * 4 + g;
  const int mshift = (l & 15) * 4;

  const float* f2p = f2g + 4 * l;
  const unsigned short* hp = hTg + (size_t)(w * 16 + (l & 15)) * NN + g * 8;

  f32x4 acc = {0.f, 0.f, 0.f, 0.f};
  float rs0 = 0.f, rs1 = 0.f, rs2 = 0.f, rs3 = 0.f;

#define PRODUCE(K, MM0, MM1, MM2, MM3, FF)                                     \
  {                                                                            \
    float F5x = LRALPHA * FF[0], F5y = LRALPHA * FF[1],                        \
          F5z = LRALPHA * FF[2], F5w = LRALPHA * FF[3];                        \
    _Pragma("unroll")                                                          \
    for (int q = 0; q < 4; ++q) {                                              \
      unsigned long long mm = q == 0 ? MM0 : q == 1 ? MM1 : q == 2 ? MM2 : MM3;\
      unsigned nib = (unsigned)(mm >> mshift) & 0xFu;                          \
      float z0 = fmaxf(c1q[q] + FF[0], c2q[q] + F5x);                          \
      float z1 = fmaxf(c1q[q] + FF[1], c2q[q] + F5y);                          \
      float z2 = fmaxf(c1q[q] + FF[2], c2q[q] + F5z);                          \
      float z3 = fmaxf(c1q[q] + FF[3], c2q[q] + F5w);                          \
      z0 = (nib & 1u) ? z0 : -1000.f;                                          \
      z1 = (nib & 2u) ? z1 : -1000.f;                                          \
      z2 = (nib & 4u) ? z2 : -1000.f;                                          \
      z3 = (nib & 8u) ? z3 : -1000.f;                                          \
      float p0 = __builtin_amdgcn_exp2f(z0);                                   \
      float p1 = __builtin_amdgcn_exp2f(z1);                                   \
      float p2 = __builtin_amdgcn_exp2f(z2);                                   \
      float p3 = __builtin_amdgcn_exp2f(z3);                                   \
      float pS = (p0 + p1) + (p2 + p3);                                        \
      if (q == 0) rs0 += pS;                                                   \
      else if (q == 1) rs1 += pS;                                              \
      else if (q == 2) rs2 += pS;                                              \
      else rs3 += pS;                                                          \
      unsigned r0 = __builtin_bit_cast(unsigned, p0) + 0x8000u;                \
      unsigned r1 = __builtin_bit_cast(unsigned, p1) + 0x8000u;                \
      unsigned r2 = __builtin_bit_cast(unsigned, p2) + 0x8000u;                \
      unsigned r3 = __builtin_bit_cast(unsigned, p3) + 0x8000u;                \
      unsigned pk01 = __builtin_amdgcn_perm(r1, r0, 0x07060302u);              \
      unsigned pk23 = __builtin_amdgcn_perm(r3, r2, 0x07060302u);              \
      unsigned long long pk = (unsigned long long)pk01 |                       \
                              ((unsigned long long)pk23 << 32);                \
      *(unsigned long long*)&Pl[(K) & 3][4 * w + q][4 * l] = pk;               \
    }                                                                          \
  }

#define LOADR(MM0, MM1, MM2, MM3, FF, K)                                       \
  { int _k = (K) < TPB ? (K) : (TPB - 1);                                      \
    int _p = p0t + _k;                                                         \
    MM0 = mr0[_p * 4]; MM1 = mr1[_p * 4];                                      \
    MM2 = mr2[_p * 4]; MM3 = mr3[_p * 4];                                      \
    FF = *(const f32x4*)(f2p + _p * TJ); }

  unsigned long long m0, m1, m2, m3;
  f32x4 ff;

  LOADR(m0, m1, m2, m3, ff, 0);
  PRODUCE(0, m0, m1, m2, m3, ff);
  LOADR(m0, m1, m2, m3, ff, 1);
  PRODUCE(1, m0, m1, m2, m3, ff);
  LOADR(m0, m1, m2, m3, ff, 2);

  for (int k = 0; k < TPB; ++k) {
    if (k < TPB - 2) {
      PRODUCE(k + 2, m0, m1, m2, m3, ff);
      LOADR(m0, m1, m2, m3, ff, k + 3);
    }
    barrier_lgkm();
    const unsigned short* pa = &Pl[k & 3][0][0] + (l & 15) * (TJ + 8) + g * 8;
    const unsigned short* pb = hp + (size_t)(p0t + k) * TJ;
#pragma unroll
    for (int kw = 0; kw < 8; ++kw) {
      bf16x8 av = *(const bf16x8*)(pa + kw * 32);
      bf16x8 bv = *(const bf16x8*)(pb + kw * 32);
      acc = __builtin_amdgcn_mfma_f32_16x16x32_bf16(av, bv, acc, 0, 0, 0);
    }
  }
#undef PRODUCE
#undef LOADR

  // wave-level row sums -> partial rs
  float rsq[4] = {rs0, rs1, rs2, rs3};
#pragma unroll
  for (int q = 0; q < 4; ++q) {
    float r = rsq[q];
#pragma unroll
    for (int off = 32; off > 0; off >>= 1)
      r += __shfl_xor(r, off);
    if (l == 0) prs[(size_t)h * NN + i0 + 4 * w + q] = r;
  }

  // partial acc: row = g*4 + q, col = w*16 + (l&15)
  float* po = pacc + (size_t)h * NN * FOUT
            + (size_t)(i0 + g * 4) * FOUT + (w * 16 + (l & 15));
#pragma unroll
  for (int q = 0; q < 4; ++q)
    po[(size_t)q * FOUT] = acc[q];
}

// ---------------------------------------------------------------------------
// kernel 4: combine halves, BN, ELU
// ---------------------------------------------------------------------------
__global__ __launch_bounds__(256) void epilogue_kernel(
    const float* __restrict__ pacc, const float* __restrict__ prs,
    const float* __restrict__ bng, const float* __restrict__ bnb,
    const float* __restrict__ bnm, const float* __restrict__ bnv,
    float* __restrict__ out)
{
  const int idx = blockIdx.x * 256 + threadIdx.x;
  const int i = idx >> 6;
  const int c = idx & 63;
  float s = pacc[idx] + pacc[(size_t)NN * FOUT + idx];
  float r = prs[i] + prs[NN + i];
  float v = s / r;
  v = (v - bnm[c]) * rsqrtf(bnv[c] + 1e-5f) * bng[c] + bnb[c];
  out[idx] = v > 0.f ? v : expm1f(v);
}

// ---------------------------------------------------------------------------
extern "C" void kernel_launch(void* const* d_in, const int* in_sizes, int n_in,
                              void* d_out, int out_size, void* d_ws, size_t ws_size,
                              hipStream_t stream)
{
  (void)in_sizes; (void)n_in; (void)out_size; (void)ws_size;
  const float* inp = (const float*)d_in[0];
  const int*   adj = (const int*)d_in[1];
  const float* Wg  = (const float*)d_in[2];
  const float* ag  = (const float*)d_in[3];
  const float* bng = (const float*)d_in[4];
  const float* bnb = (const float*)d_in[5];
  const float* bnm = (const float*)d_in[6];
  const float* bnv = (const float*)d_in[7];
  float* out = (float*)d_out;

  char* ws = (char*)d_ws;
  unsigned short* hT = (unsigned short*)ws;                      // 1 MiB
  float* f1  = (float*)(ws + (size_t)NN * FOUT * 2);             // 32 KiB
  float* f2  = f1 + NN;                                          // 32 KiB
  float* f2m = f2 + NN;                                          // 4 B
  unsigned long long* mask =
      (unsigned long long*)(ws + (size_t)2 * 1024 * 1024);       // 8 MiB
  float* pacc = (float*)(ws + (size_t)10 * 1024 * 1024);         // 4 MiB
  float* prs  = (float*)(ws + (size_t)14 * 1024 * 1024);         // 64 KiB

  compress_kernel<<<2048, 256, 0, stream>>>(adj, mask);
  prep_kernel<<<NN / 16, 256, 0, stream>>>(inp, Wg, ag, f1, f2, hT);
  f2max_kernel<<<1, 256, 0, stream>>>(f2, f2m);
  gat_main<<<(NN / TI) * 2, 256, 0, stream>>>(mask, f1, f2, f2m, hT, pacc, prs);
  epilogue_kernel<<<NN * FOUT / 256, 256, 0, stream>>>(pacc, prs, bng, bnb,
                                                       bnm, bnv, out);
}

// Round 7
// 145.043 us; speedup vs baseline: 1.0321x; 1.0052x over previous
//
#include <hip/hip_runtime.h>
#include <hip/hip_bf16.h>

#define LRALPHA 0.2f
#define L2E 1.4426950408889634f
#define NN 8192
#define FIN 128
#define FOUT 64
#define TI 16
#define TJ 256
#define NTL (NN / TJ)       // 32 tiles of 256 cols
#define TPB 16              // tiles per block (j-range split in half)

typedef __attribute__((ext_vector_type(4))) float f32x4;
typedef __attribute__((ext_vector_type(8))) short bf16x8;
typedef __attribute__((ext_vector_type(4))) int int4v;

__device__ __forceinline__ void barrier_lgkm() {
  asm volatile("s_waitcnt lgkmcnt(0)\n\ts_barrier" ::: "memory");
}

// ---------------------------------------------------------------------------
// kernel 0: adj (268 MB int32) -> 1-bit mask (8 MB), m13-copy shape:
// thread-linear grid-stride, 2x dwordx4 (32 B/lane/iter), per-lane byte
// stores (no ballot, no exec-masked store). Byte layout identical to the
// previous u64 mask: maskb[i*1024 + jb] bit b = adj[i][jb*8+b] > 0.
// ---------------------------------------------------------------------------
__global__ __launch_bounds__(256) void compress_kernel(
    const int* __restrict__ adj, unsigned char* __restrict__ maskb)
{
  const int nthr = gridDim.x * 256;
  const int total = NN * (NN / 8);              // 8,388,608 byte-slots
#pragma unroll 2
  for (int idx = blockIdx.x * 256 + threadIdx.x; idx < total; idx += nthr) {
    int4v v0 = *(const int4v*)(adj + (size_t)idx * 8);
    int4v v1 = *(const int4v*)(adj + (size_t)idx * 8 + 4);
    unsigned b =
        (v0[0] > 0 ? 1u : 0u)  | (v0[1] > 0 ? 2u : 0u) |
        (v0[2] > 0 ? 4u : 0u)  | (v0[3] > 0 ? 8u : 0u) |
        (v1[0] > 0 ? 16u : 0u) | (v1[1] > 0 ? 32u : 0u) |
        (v1[2] > 0 ? 64u : 0u) | (v1[3] > 0 ? 128u : 0u);
    maskb[idx] = (unsigned char)b;
  }
}

// ---------------------------------------------------------------------------
// kernel 1: h = inp @ W (fp32), f1/f2 (prescaled by log2(e)), hT bf16
// ---------------------------------------------------------------------------
__global__ __launch_bounds__(256) void prep_kernel(
    const float* __restrict__ inp, const float* __restrict__ Wg,
    const float* __restrict__ ag, float* __restrict__ f1,
    float* __restrict__ f2, unsigned short* __restrict__ hT)
{
  __shared__ alignas(16) float WlT[FOUT][FIN + 4];
  const int t = threadIdx.x;
  for (int i = t; i < FIN * FOUT; i += 256)
    WlT[i & 63][i >> 6] = Wg[i];
  __syncthreads();

  const int lane = t & 63;
  const int row0 = blockIdx.x * 16 + (t >> 6) * 4;

  float h0 = 0.f, h1 = 0.f, h2 = 0.f, h3 = 0.f;
  for (int kk = 0; kk < FIN; kk += 4) {
    f32x4 wv = *(const f32x4*)&WlT[lane][kk];
    f32x4 r0 = *(const f32x4*)&inp[(row0 + 0) * FIN + kk];
    f32x4 r1 = *(const f32x4*)&inp[(row0 + 1) * FIN + kk];
    f32x4 r2 = *(const f32x4*)&inp[(row0 + 2) * FIN + kk];
    f32x4 r3 = *(const f32x4*)&inp[(row0 + 3) * FIN + kk];
    h0 += r0[0]*wv[0] + r0[1]*wv[1] + r0[2]*wv[2] + r0[3]*wv[3];
    h1 += r1[0]*wv[0] + r1[1]*wv[1] + r1[2]*wv[2] + r1[3]*wv[3];
    h2 += r2[0]*wv[0] + r2[1]*wv[1] + r2[2]*wv[2] + r2[3]*wv[3];
    h3 += r3[0]*wv[0] + r3[1]*wv[1] + r3[2]*wv[2] + r3[3]*wv[3];
  }

  const float a1v = ag[lane], a2v = ag[64 + lane];
  float hv[4] = {h0, h1, h2, h3};
#pragma unroll
  for (int rr = 0; rr < 4; ++rr) {
    float c1 = hv[rr] * a1v;
    float c2 = hv[rr] * a2v;
#pragma unroll
    for (int off = 32; off > 0; off >>= 1) {
      c1 += __shfl_xor(c1, off);
      c2 += __shfl_xor(c2, off);
    }
    if (lane == 0) { f1[row0 + rr] = c1 * L2E; f2[row0 + rr] = c2 * L2E; }
    __hip_bfloat16 hb = __float2bfloat16(hv[rr]);
    hT[lane * NN + row0 + rr] = __builtin_bit_cast(unsigned short, hb);
  }
}

// ---------------------------------------------------------------------------
// kernel 2: global max of (scaled) f2
// ---------------------------------------------------------------------------
__global__ __launch_bounds__(256) void f2max_kernel(
    const float* __restrict__ f2, float* __restrict__ f2m)
{
  const int t = threadIdx.x;
  float m = -1e30f;
  for (int i = t; i < NN / 4; i += 256) {
    f32x4 v = ((const f32x4*)f2)[i];
    m = fmaxf(fmaxf(m, fmaxf(v[0], v[1])), fmaxf(v[2], v[3]));
  }
#pragma unroll
  for (int off = 32; off > 0; off >>= 1)
    m = fmaxf(m, __shfl_xor(m, off));
  __shared__ float ms[4];
  if ((t & 63) == 0) ms[t >> 6] = m;
  __syncthreads();
  if (t == 0)
    f2m[0] = fmaxf(fmaxf(ms[0], ms[1]), fmaxf(ms[2], ms[3]));
}

// ---------------------------------------------------------------------------
// kernel 3: masked-softmax attention PV, mask-fed, exp2-domain P-gen,
// v_perm bf16 packing. grid = 1024 (row-block x j-half), 4 blocks/CU.
// Partial acc/rowsum -> ws; epilogue combines. (UNCHANGED from R6.)
// ---------------------------------------------------------------------------
__global__ __launch_bounds__(256, 4) void gat_main(
    const unsigned long long* __restrict__ mask,
    const float* __restrict__ f1g, const float* __restrict__ f2g,
    const float* __restrict__ f2m, const unsigned short* __restrict__ hTg,
    float* __restrict__ pacc, float* __restrict__ prs)
{
  __shared__ alignas(16) unsigned short Pl[4][TI][TJ + 8];

  const int t = threadIdx.x;
  const int l = t & 63;
  const int w = t >> 6;
  const int rb = blockIdx.x >> 1;
  const int h  = blockIdx.x & 1;
  const int i0 = rb * TI;
  const int g  = l >> 4;
  const int p0t = h * TPB;

  const float fmv = f2m[0];
  float c1q[4], c2q[4];
#pragma unroll
  for (int q = 0; q < 4; ++q) {
    float f1s = f1g[i0 + 4 * w + q];
    float M = f1s + fmv;
    float mr = fmaxf(M, LRALPHA * M);
    c1q[q] = f1s - mr;
    c2q[q] = LRALPHA * f1s - mr;
  }

  const unsigned long long* mr0 = mask + ((size_t)(i0 + 4*w + 0) * NTL) * 4 + g;
  const unsigned long long* mr1 = mask + ((size_t)(i0 + 4*w + 1) * NTL) * 4 + g;
  const unsigned long long* mr2 = mask + ((size_t)(i0 + 4*w + 2) * NTL) * 4 + g;
  const unsigned long long* mr3 = mask + ((size_t)(i0 + 4*w + 3) * NTL) * 4 + g;
  const int mshift = (l & 15) * 4;

  const float* f2p = f2g + 4 * l;
  const unsigned short* hp = hTg + (size_t)(w * 16 + (l & 15)) * NN + g * 8;

  f32x4 acc = {0.f, 0.f, 0.f, 0.f};
  float rs0 = 0.f, rs1 = 0.f, rs2 = 0.f, rs3 = 0.f;

#define PRODUCE(K, MM0, MM1, MM2, MM3, FF)                                     \
  {                                                                            \
    float F5x = LRALPHA * FF[0], F5y = LRALPHA * FF[1],                        \
          F5z = LRALPHA * FF[2], F5w = LRALPHA * FF[3];                        \
    _Pragma("unroll")                                                          \
    for (int q = 0; q < 4; ++q) {                                              \
      unsigned long long mm = q == 0 ? MM0 : q == 1 ? MM1 : q == 2 ? MM2 : MM3;\
      unsigned nib = (unsigned)(mm >> mshift) & 0xFu;                          \
      float z0 = fmaxf(c1q[q] + FF[0], c2q[q] + F5x);                          \
      float z1 = fmaxf(c1q[q] + FF[1], c2q[q] + F5y);                          \
      float z2 = fmaxf(c1q[q] + FF[2], c2q[q] + F5z);                          \
      float z3 = fmaxf(c1q[q] + FF[3], c2q[q] + F5w);                          \
      z0 = (nib & 1u) ? z0 : -1000.f;                                          \
      z1 = (nib & 2u) ? z1 : -1000.f;                                          \
      z2 = (nib & 4u) ? z2 : -1000.f;                                          \
      z3 = (nib & 8u) ? z3 : -1000.f;                                          \
      float p0 = __builtin_amdgcn_exp2f(z0);                                   \
      float p1 = __builtin_amdgcn_exp2f(z1);                                   \
      float p2 = __builtin_amdgcn_exp2f(z2);                                   \
      float p3 = __builtin_amdgcn_exp2f(z3);                                   \
      float pS = (p0 + p1) + (p2 + p3);                                        \
      if (q == 0) rs0 += pS;                                                   \
      else if (q == 1) rs1 += pS;                                              \
      else if (q == 2) rs2 += pS;                                              \
      else rs3 += pS;                                                          \
      unsigned r0 = __builtin_bit_cast(unsigned, p0) + 0x8000u;                \
      unsigned r1 = __builtin_bit_cast(unsigned, p1) + 0x8000u;                \
      unsigned r2 = __builtin_bit_cast(unsigned, p2) + 0x8000u;                \
      unsigned r3 = __builtin_bit_cast(unsigned, p3) + 0x8000u;                \
      unsigned pk01 = __builtin_amdgcn_perm(r1, r0, 0x07060302u);              \
      unsigned pk23 = __builtin_amdgcn_perm(r3, r2, 0x07060302u);              \
      unsigned long long pk = (unsigned long long)pk01 |                       \
                              ((unsigned long long)pk23 << 32);                \
      *(unsigned long long*)&Pl[(K) & 3][4 * w + q][4 * l] = pk;               \
    }                                                                          \
  }

#define LOADR(MM0, MM1, MM2, MM3, FF, K)                                       \
  { int _k = (K) < TPB ? (K) : (TPB - 1);                                      \
    int _p = p0t + _k;                                                         \
    MM0 = mr0[_p * 4]; MM1 = mr1[_p * 4];                                      \
    MM2 = mr2[_p * 4]; MM3 = mr3[_p * 4];                                      \
    FF = *(const f32x4*)(f2p + _p * TJ); }

  unsigned long long m0, m1, m2, m3;
  f32x4 ff;

  LOADR(m0, m1, m2, m3, ff, 0);
  PRODUCE(0, m0, m1, m2, m3, ff);
  LOADR(m0, m1, m2, m3, ff, 1);
  PRODUCE(1, m0, m1, m2, m3, ff);
  LOADR(m0, m1, m2, m3, ff, 2);

  for (int k = 0; k < TPB; ++k) {
    if (k < TPB - 2) {
      PRODUCE(k + 2, m0, m1, m2, m3, ff);
      LOADR(m0, m1, m2, m3, ff, k + 3);
    }
    barrier_lgkm();
    const unsigned short* pa = &Pl[k & 3][0][0] + (l & 15) * (TJ + 8) + g * 8;
    const unsigned short* pb = hp + (size_t)(p0t + k) * TJ;
#pragma unroll
    for (int kw = 0; kw < 8; ++kw) {
      bf16x8 av = *(const bf16x8*)(pa + kw * 32);
      bf16x8 bv = *(const bf16x8*)(pb + kw * 32);
      acc = __builtin_amdgcn_mfma_f32_16x16x32_bf16(av, bv, acc, 0, 0, 0);
    }
  }
#undef PRODUCE
#undef LOADR

  // wave-level row sums -> partial rs
  float rsq[4] = {rs0, rs1, rs2, rs3};
#pragma unroll
  for (int q = 0; q < 4; ++q) {
    float r = rsq[q];
#pragma unroll
    for (int off = 32; off > 0; off >>= 1)
      r += __shfl_xor(r, off);
    if (l == 0) prs[(size_t)h * NN + i0 + 4 * w + q] = r;
  }

  // partial acc: row = g*4 + q, col = w*16 + (l&15)
  float* po = pacc + (size_t)h * NN * FOUT
            + (size_t)(i0 + g * 4) * FOUT + (w * 16 + (l & 15));
#pragma unroll
  for (int q = 0; q < 4; ++q)
    po[(size_t)q * FOUT] = acc[q];
}

// ---------------------------------------------------------------------------
// kernel 4: combine halves, BN, ELU
// ---------------------------------------------------------------------------
__global__ __launch_bounds__(256) void epilogue_kernel(
    const float* __restrict__ pacc, const float* __restrict__ prs,
    const float* __restrict__ bng, const float* __restrict__ bnb,
    const float* __restrict__ bnm, const float* __restrict__ bnv,
    float* __restrict__ out)
{
  const int idx = blockIdx.x * 256 + threadIdx.x;
  const int i = idx >> 6;
  const int c = idx & 63;
  float s = pacc[idx] + pacc[(size_t)NN * FOUT + idx];
  float r = prs[i] + prs[NN + i];
  float v = s / r;
  v = (v - bnm[c]) * rsqrtf(bnv[c] + 1e-5f) * bng[c] + bnb[c];
  out[idx] = v > 0.f ? v : expm1f(v);
}

// ---------------------------------------------------------------------------
extern "C" void kernel_launch(void* const* d_in, const int* in_sizes, int n_in,
                              void* d_out, int out_size, void* d_ws, size_t ws_size,
                              hipStream_t stream)
{
  (void)in_sizes; (void)n_in; (void)out_size; (void)ws_size;
  const float* inp = (const float*)d_in[0];
  const int*   adj = (const int*)d_in[1];
  const float* Wg  = (const float*)d_in[2];
  const float* ag  = (const float*)d_in[3];
  const float* bng = (const float*)d_in[4];
  const float* bnb = (const float*)d_in[5];
  const float* bnm = (const float*)d_in[6];
  const float* bnv = (const float*)d_in[7];
  float* out = (float*)d_out;

  char* ws = (char*)d_ws;
  unsigned short* hT = (unsigned short*)ws;                      // 1 MiB
  float* f1  = (float*)(ws + (size_t)NN * FOUT * 2);             // 32 KiB
  float* f2  = f1 + NN;                                          // 32 KiB
  float* f2m = f2 + NN;                                          // 4 B
  unsigned char* maskb = (unsigned char*)(ws + (size_t)2 * 1024 * 1024);
  unsigned long long* mask = (unsigned long long*)maskb;         // 8 MiB
  float* pacc = (float*)(ws + (size_t)10 * 1024 * 1024);         // 4 MiB
  float* prs  = (float*)(ws + (size_t)14 * 1024 * 1024);         // 64 KiB

  compress_kernel<<<2048, 256, 0, stream>>>(adj, maskb);
  prep_kernel<<<NN / 16, 256, 0, stream>>>(inp, Wg, ag, f1, f2, hT);
  f2max_kernel<<<1, 256, 0, stream>>>(f2, f2m);
  gat_main<<<(NN / TI) * 2, 256, 0, stream>>>(mask, f1, f2, f2m, hT, pacc, prs);
  epilogue_kernel<<<NN * FOUT / 256, 256, 0, stream>>>(pacc, prs, bng, bnb,
                                                       bnm, bnv, out);
}